// Round 2
// baseline (428.023 us; speedup 1.0000x reference)
//
#include <hip/hip_runtime.h>

typedef unsigned short u16;
typedef __bf16 bf16x8 __attribute__((ext_vector_type(8)));
typedef __bf16 bf16x4 __attribute__((ext_vector_type(4)));
typedef float f32x4 __attribute__((ext_vector_type(4)));
typedef u16 u16x8 __attribute__((ext_vector_type(8), may_alias));
typedef u16 u16x4 __attribute__((ext_vector_type(4), may_alias));
typedef unsigned int u32x2 __attribute__((ext_vector_type(2)));

#define D_MODEL 1024
#define D_MLP   4096
#define D_HEAD  64
#define N_HEADS 16
#define SEQ     2048
#define BATCH   2
#define BS      (BATCH * SEQ)   // 4096 rows
#define QKV_N   3072
// Q pre-scale: (1/sqrt(64)) * log2(e) so attention works in exp2 domain
#define QSCALE  0.18033688011112042f

__device__ __forceinline__ u16 f2b(float f) {
  unsigned u = __builtin_bit_cast(unsigned, f);
  u += 0x7fffu + ((u >> 16) & 1u);           // round-to-nearest-even
  return (u16)(u >> 16);
}

__device__ __forceinline__ unsigned cvtpk_bf16(float lo, float hi) {
  unsigned r;
  asm("v_cvt_pk_bf16_f32 %0, %1, %2" : "=v"(r) : "v"(lo), "v"(hi));
  return r;
}

__device__ __forceinline__ f32x4 mfma16(bf16x4 a, bf16x4 b, f32x4 c) {
#if __has_builtin(__builtin_amdgcn_mfma_f32_16x16x16bf16_1k)
  typedef short s16x4 __attribute__((ext_vector_type(4)));
  return __builtin_amdgcn_mfma_f32_16x16x16bf16_1k(
      __builtin_bit_cast(s16x4, a), __builtin_bit_cast(s16x4, b), c, 0, 0, 0);
#else
  asm volatile("s_nop 1\n\tv_mfma_f32_16x16x16_bf16 %0, %1, %2, %0"
               : "+v"(c) : "v"(a), "v"(b));
  return c;
#endif
}

__device__ __forceinline__ void gload_lds16(const u16* g, u16* l) {
  __builtin_amdgcn_global_load_lds(
      (const __attribute__((address_space(1))) unsigned int*)g,
      (__attribute__((address_space(3))) unsigned int*)l, 16, 0, 0);
}

// ---------------- fp32 -> bf16 convert (4 elems/thread) ----------------
__global__ __launch_bounds__(256) void cvt_kernel(const float* __restrict__ in,
                                                  u16* __restrict__ out, int n4) {
  int i = blockIdx.x * 256 + threadIdx.x;
  if (i >= n4) return;
  float4 v = ((const float4*)in)[i];
  u16x4 o;
  o[0] = f2b(v.x); o[1] = f2b(v.y); o[2] = f2b(v.z); o[3] = f2b(v.w);
  ((u16x4*)out)[i] = o;
}

// ---------------- generic bf16 GEMM: C[M,N] = A[M,K] @ B[N,K]^T ----------------
// 128x128 tile, BK=64, 4 waves, 16x16x32 MFMA, global_load_lds(16B),
// XOR slot-swizzle applied to the GLOBAL source (LDS stays linear) + same XOR on reads.
// MODE 0: QKV. col<1024: Q*QSCALE -> qk (LD 2048); col<2048: K -> qk; else V -> vt transposed
// MODE 1: o = acc + resid[idx]; outf = o; outb = bf16(o)     (attn out + residual)
// MODE 2: o = relu(acc + bias[col]); outb = bf16(o)          (mlp in)
// MODE 3: outf = acc + resid[idx] + bias[col]                (mlp out -> d_out)
template<int MODE>
__global__ __launch_bounds__(256) void gemm_bt(
    const u16* __restrict__ A, const u16* __restrict__ Bw,
    int M, int N, int K,
    u16* __restrict__ outb, float* __restrict__ outf,
    const float* __restrict__ resid, const float* __restrict__ bias,
    u16* __restrict__ vtp)
{
  __shared__ u16 Asm_[128 * 64];
  __shared__ u16 Bsm_[128 * 64];
  const int t = threadIdx.x;
  const int lane = t & 63;
  const int l15 = lane & 15, l4 = lane >> 4;
  const int w = t >> 6;
  const int wr = w >> 1, wc = w & 1;
  const int m0 = blockIdx.y * 128;
  const int n0 = blockIdx.x * 128;

  f32x4 acc[4][4] = {};

  for (int k0 = 0; k0 < K; k0 += 64) {
    __syncthreads();
#pragma unroll
    for (int i = 0; i < 4; ++i) {
      int s = i * 256 + t;                 // 16B slot index 0..1023
      int row = s >> 3;
      int sl = s & 7;
      int gc = ((sl ^ (row & 7)) << 3);    // pre-swizzled global k-chunk
      const u16* ga = A + (size_t)(m0 + row) * K + (k0 + gc);
      const u16* gb = Bw + (size_t)(n0 + row) * K + (k0 + gc);
      u16* la = Asm_ + (i * 256 + (t & ~63)) * 8;   // wave-uniform base
      u16* lb = Bsm_ + (i * 256 + (t & ~63)) * 8;
      gload_lds16(ga, la);
      gload_lds16(gb, lb);
    }
    asm volatile("s_waitcnt vmcnt(0)" ::: "memory");
    __syncthreads();
#pragma unroll
    for (int kk = 0; kk < 2; ++kk) {
      bf16x8 af[4], bfr[4];
#pragma unroll
      for (int mi = 0; mi < 4; ++mi) {
        int row = wr * 64 + mi * 16 + l15;
        int sl2 = (kk * 4 + l4) ^ (row & 7);
        u16x8 ua = *(const u16x8*)(Asm_ + row * 64 + sl2 * 8);
        af[mi] = __builtin_bit_cast(bf16x8, ua);
      }
#pragma unroll
      for (int ni = 0; ni < 4; ++ni) {
        int row = wc * 64 + ni * 16 + l15;
        int sl2 = (kk * 4 + l4) ^ (row & 7);
        u16x8 ub = *(const u16x8*)(Bsm_ + row * 64 + sl2 * 8);
        bfr[ni] = __builtin_bit_cast(bf16x8, ub);
      }
#pragma unroll
      for (int mi = 0; mi < 4; ++mi)
#pragma unroll
        for (int ni = 0; ni < 4; ++ni)
          acc[mi][ni] = __builtin_amdgcn_mfma_f32_16x16x32_bf16(af[mi], bfr[ni], acc[mi][ni], 0, 0, 0);
    }
  }

#pragma unroll
  for (int mi = 0; mi < 4; ++mi) {
    int rowb = m0 + wr * 64 + mi * 16 + l4 * 4;
#pragma unroll
    for (int ni = 0; ni < 4; ++ni) {
      int col = n0 + wc * 64 + ni * 16 + l15;
#pragma unroll
      for (int r = 0; r < 4; ++r) {
        float v = acc[mi][ni][r];
        int row = rowb + r;
        if (MODE == 0) {
          if (col < 2048) {
            float o = (col < 1024) ? v * QSCALE : v;
            outb[((size_t)row << 11) + col] = f2b(o);
          } else {
            int c = col - 2048;                       // c = h*64 + d
            size_t vi = (((size_t)((row >> 11) * 1024 + c)) << 11) + (row & (SEQ - 1));
            vtp[vi] = f2b(v);
          }
        } else {
          size_t idx = (size_t)row * N + col;
          if (MODE == 1) {
            float o = v + resid[idx];
            outf[idx] = o;
            outb[idx] = f2b(o);
          } else if (MODE == 2) {
            float o = v + bias[col];
            o = o > 0.f ? o : 0.f;
            outb[idx] = f2b(o);
          } else {
            outf[idx] = v + resid[idx] + bias[col];
          }
        }
      }
    }
  }
}

// ---------------- causal flash attention, LDS-free ----------------
// One wave per (b, h, 16 query rows). Key tiles of 32.
// qk layout [BS][2048]: Q(prescaled)|K.  vT layout [(b*16+h)*64 + d][SEQ].
// Scores computed TRANSPOSED: sf = mfma(K, Q) -> lane holds S[p=sub*16+l4*4+r][q=l15],
// so softmax is lane-local + 2 shfl_xor, and P quads are directly the A-frag
// of v_mfma_f32_16x16x16_bf16 for PV (zero LDS, zero P re-layout).
__global__ __launch_bounds__(256) void attn_kernel(const u16* __restrict__ qk,
                                                   const u16* __restrict__ vT,
                                                   u16* __restrict__ zb)
{
  const int t = threadIdx.x;
  const int w = t >> 6;
  const int lane = t & 63;
  const int l15 = lane & 15, l4 = lane >> 4;
  const int uu = blockIdx.x * 4 + w;
  const int qt = uu >> 5;                 // 128 q-tiles per (b,h); B*H = 32
  const int bh = uu & 31;
  const int b = bh >> 4, h = bh & 15;
  const int q0 = qt * 16;

  // Q fragments (B-operand of the score mfma): Q[q0+l15][kc*32 + l4*8 .. +7]
  const u16* qptr = qk + (((size_t)(b * SEQ + q0 + l15)) << 11) + h * 64 + l4 * 8;
  const bf16x8 qf0 = __builtin_bit_cast(bf16x8, *(const u16x8*)(qptr));
  const bf16x8 qf1 = __builtin_bit_cast(bf16x8, *(const u16x8*)(qptr + 32));

  // K row pointers (A-operand): K[p0 + sub*16 + l15][kc*32 + l4*8]
  const u16* kp0 = qk + (((size_t)(b * SEQ + l15)) << 11) + 1024 + h * 64 + l4 * 8;
  const u16* kp1 = kp0 + ((size_t)16 << 11);
  // V^T pointers (B-operand of PV): vT[d = dn*16+l15][p0 + sub*16 + l4*4 .. +3]
  const u16* vbase = vT + ((((size_t)bh) * 64 + l15) << 11) + l4 * 4;
  const u16* vp0 = vbase;
  const u16* vp1 = vbase + ((size_t)16 << 11);
  const u16* vp2 = vbase + ((size_t)32 << 11);
  const u16* vp3 = vbase + ((size_t)48 << 11);

  f32x4 zacc[4] = {};
  float m_run = -1e30f, l_run = 0.f;

  const int nfull = q0 >> 5;              // full (unmasked) 32-key tiles
  for (int pt = 0; pt <= nfull; ++pt) {
    bf16x8 k00 = __builtin_bit_cast(bf16x8, *(const u16x8*)(kp0));
    bf16x8 k01 = __builtin_bit_cast(bf16x8, *(const u16x8*)(kp0 + 32));
    bf16x8 k10 = __builtin_bit_cast(bf16x8, *(const u16x8*)(kp1));
    bf16x8 k11 = __builtin_bit_cast(bf16x8, *(const u16x8*)(kp1 + 32));
    f32x4 s0 = {}, s1 = {};
    s0 = __builtin_amdgcn_mfma_f32_16x16x32_bf16(k00, qf0, s0, 0, 0, 0);
    s0 = __builtin_amdgcn_mfma_f32_16x16x32_bf16(k01, qf1, s0, 0, 0, 0);
    s1 = __builtin_amdgcn_mfma_f32_16x16x32_bf16(k10, qf0, s1, 0, 0, 0);
    s1 = __builtin_amdgcn_mfma_f32_16x16x32_bf16(k11, qf1, s1, 0, 0, 0);

    if (pt == nfull) {                    // only the last tile straddles the diagonal
      const int qq = q0 + l15;
      const int pb = pt * 32 + l4 * 4;
#pragma unroll
      for (int r = 0; r < 4; ++r) {
        s0[r] = (pb + r <= qq) ? s0[r] : -1e30f;
        s1[r] = (pb + 16 + r <= qq) ? s1[r] : -1e30f;
      }
    }

    // online softmax over p (lane-local 8 values + reduce across l4 groups)
    float mt = fmaxf(fmaxf(fmaxf(s0[0], s0[1]), fmaxf(s0[2], s0[3])),
                     fmaxf(fmaxf(s1[0], s1[1]), fmaxf(s1[2], s1[3])));
    mt = fmaxf(mt, __shfl_xor(mt, 16));
    mt = fmaxf(mt, __shfl_xor(mt, 32));
    const float mn = fmaxf(m_run, mt);
    const float sc = exp2f(m_run - mn);
    m_run = mn;
    float p0v[4], p1v[4];
    float rs = 0.f;
#pragma unroll
    for (int r = 0; r < 4; ++r) {
      p0v[r] = exp2f(s0[r] - mn);
      p1v[r] = exp2f(s1[r] - mn);
      rs += p0v[r] + p1v[r];
    }
    rs += __shfl_xor(rs, 16);
    rs += __shfl_xor(rs, 32);
    l_run = l_run * sc + rs;

    // rescale accumulator (per-row factor lives in lanes 0..15)
    float scr[4];
#pragma unroll
    for (int r = 0; r < 4; ++r) scr[r] = __shfl(sc, l4 * 4 + r);
#pragma unroll
    for (int dn = 0; dn < 4; ++dn)
#pragma unroll
      for (int r = 0; r < 4; ++r) zacc[dn][r] *= scr[r];

    // pack P to bf16 A-frags (quad p = sub*16 + l4*4 .. +3 for q=l15)
    u32x2 ua, ub2;
    ua[0] = cvtpk_bf16(p0v[0], p0v[1]);
    ua[1] = cvtpk_bf16(p0v[2], p0v[3]);
    ub2[0] = cvtpk_bf16(p1v[0], p1v[1]);
    ub2[1] = cvtpk_bf16(p1v[2], p1v[3]);
    const bf16x4 pa0 = __builtin_bit_cast(bf16x4, ua);
    const bf16x4 pa1 = __builtin_bit_cast(bf16x4, ub2);

    // PV: z[q, dn*16+l15] += P V
    {
      bf16x4 vb0 = __builtin_bit_cast(bf16x4, *(const u16x4*)(vp0));
      bf16x4 vb1 = __builtin_bit_cast(bf16x4, *(const u16x4*)(vp0 + 16));
      zacc[0] = mfma16(pa0, vb0, zacc[0]);
      zacc[0] = mfma16(pa1, vb1, zacc[0]);
    }
    {
      bf16x4 vb0 = __builtin_bit_cast(bf16x4, *(const u16x4*)(vp1));
      bf16x4 vb1 = __builtin_bit_cast(bf16x4, *(const u16x4*)(vp1 + 16));
      zacc[1] = mfma16(pa0, vb0, zacc[1]);
      zacc[1] = mfma16(pa1, vb1, zacc[1]);
    }
    {
      bf16x4 vb0 = __builtin_bit_cast(bf16x4, *(const u16x4*)(vp2));
      bf16x4 vb1 = __builtin_bit_cast(bf16x4, *(const u16x4*)(vp2 + 16));
      zacc[2] = mfma16(pa0, vb0, zacc[2]);
      zacc[2] = mfma16(pa1, vb1, zacc[2]);
    }
    {
      bf16x4 vb0 = __builtin_bit_cast(bf16x4, *(const u16x4*)(vp3));
      bf16x4 vb1 = __builtin_bit_cast(bf16x4, *(const u16x4*)(vp3 + 16));
      zacc[3] = mfma16(pa0, vb0, zacc[3]);
      zacc[3] = mfma16(pa1, vb1, zacc[3]);
    }

    kp0 += (size_t)32 << 11;
    kp1 += (size_t)32 << 11;
    vp0 += 32; vp1 += 32; vp2 += 32; vp3 += 32;
  }

  asm volatile("s_nop 7\n\ts_nop 7");     // MFMA->VALU hazard guard (asm-fallback path)

  const float inv = 1.f / l_run;
  float invr[4];
#pragma unroll
  for (int r = 0; r < 4; ++r) invr[r] = __shfl(inv, l4 * 4 + r);
#pragma unroll
  for (int r = 0; r < 4; ++r) {
    const size_t rowoff = ((size_t)(b * SEQ + q0 + l4 * 4 + r)) * D_MODEL + h * 64 + l15;
#pragma unroll
    for (int dn = 0; dn < 4; ++dn)
      zb[rowoff + dn * 16] = f2b(zacc[dn][r] * invr[r]);
  }
}

// ---------------- launch ----------------
extern "C" void kernel_launch(void* const* d_in, const int* in_sizes, int n_in,
                              void* d_out, int out_size, void* d_ws, size_t ws_size,
                              hipStream_t stream) {
  const float* x     = (const float*)d_in[0];
  const float* W_K   = (const float*)d_in[1];
  const float* W_Q   = (const float*)d_in[2];
  const float* W_V   = (const float*)d_in[3];
  const float* W_O   = (const float*)d_in[4];
  const float* W_in  = (const float*)d_in[5];
  const float* b_in  = (const float*)d_in[6];
  const float* W_out = (const float*)d_in[7];
  const float* b_out = (const float*)d_in[8];
  float* out = (float*)d_out;

  char* p = (char*)d_ws;
  u16* xb    = (u16*)p;            p += (size_t)BS * D_MODEL * 2;
  u16* wqkv  = (u16*)p;            p += (size_t)QKV_N * D_MODEL * 2;
  u16* wo_b  = (u16*)p;            p += (size_t)D_MODEL * D_MODEL * 2;
  u16* win_b = (u16*)p;            p += (size_t)D_MLP * D_MODEL * 2;
  u16* wout_b= (u16*)p;            p += (size_t)D_MODEL * D_MLP * 2;
  u16* qk    = (u16*)p;            p += (size_t)BS * 2048 * 2;        // Q|K, LD 2048
  u16* vt    = (u16*)p;            p += (size_t)BATCH * 1024 * SEQ * 2; // V^T per (b,h,d)
  u16* zb    = (u16*)p;            p += (size_t)BS * D_MODEL * 2;
  float* x1f = (float*)p;          p += (size_t)BS * D_MODEL * 4;
  u16* x1b   = (u16*)p;            p += (size_t)BS * D_MODEL * 2;
  u16* hb    = (u16*)p;            p += (size_t)BS * D_MLP * 2;

  auto cvt = [&](const float* src, u16* dst, int n) {
    int n4 = n / 4;
    cvt_kernel<<<(n4 + 255) / 256, 256, 0, stream>>>(src, dst, n4);
  };
  cvt(x, xb, BS * D_MODEL);
  cvt(W_Q, wqkv + 0,                  N_HEADS * D_HEAD * D_MODEL);
  cvt(W_K, wqkv + 1024 * 1024,        N_HEADS * D_HEAD * D_MODEL);
  cvt(W_V, wqkv + 2 * 1024 * 1024,    N_HEADS * D_HEAD * D_MODEL);
  cvt(W_O, wo_b,  D_MODEL * D_MODEL);
  cvt(W_in, win_b, D_MLP * D_MODEL);
  cvt(W_out, wout_b, D_MODEL * D_MLP);

  // QKV projection: [4096,1024] @ [3072,1024]^T -> qk (Q prescaled | K) + vt (V^T)
  gemm_bt<0><<<dim3(QKV_N / 128, BS / 128), 256, 0, stream>>>(
      xb, wqkv, BS, QKV_N, D_MODEL, qk, nullptr, nullptr, nullptr, vt);

  // attention: 4096 wave-units / 4 per block
  attn_kernel<<<dim3(BS * N_HEADS / 16 / 4), 256, 0, stream>>>(qk, vt, zb);

  // attn out + residual: z @ W_O^T + x -> x1 (f32 + bf16)
  gemm_bt<1><<<dim3(D_MODEL / 128, BS / 128), 256, 0, stream>>>(
      zb, wo_b, BS, D_MODEL, D_MODEL, x1b, x1f, x, nullptr, nullptr);

  // MLP in: relu(x1 @ W_in^T + b_in) -> h
  gemm_bt<2><<<dim3(D_MLP / 128, BS / 128), 256, 0, stream>>>(
      x1b, win_b, BS, D_MLP, D_MODEL, hb, nullptr, nullptr, b_in, nullptr);

  // MLP out: x1 + h @ W_out^T + b_out -> out (f32)
  gemm_bt<3><<<dim3(D_MODEL / 128, BS / 128), 256, 0, stream>>>(
      hb, wout_b, BS, D_MODEL, D_MLP, nullptr, out, x1f, b_out, nullptr);
}

// Round 3
// 427.916 us; speedup vs baseline: 1.0003x; 1.0003x over previous
//
#include <hip/hip_runtime.h>

typedef unsigned short u16;
typedef __bf16 bf16x8 __attribute__((ext_vector_type(8)));
typedef __bf16 bf16x4 __attribute__((ext_vector_type(4)));
typedef float f32x4 __attribute__((ext_vector_type(4)));
typedef u16 u16x8 __attribute__((ext_vector_type(8), may_alias));
typedef u16 u16x4 __attribute__((ext_vector_type(4), may_alias));
typedef unsigned int u32x2 __attribute__((ext_vector_type(2)));
typedef short s16x4 __attribute__((ext_vector_type(4)));

#define D_MODEL 1024
#define D_MLP   4096
#define D_HEAD  64
#define N_HEADS 16
#define SEQ     2048
#define BATCH   2
#define BS      (BATCH * SEQ)   // 4096 rows
#define QKV_N   3072
// Q pre-scale: (1/sqrt(64)) * log2(e) so attention works in exp2 domain
#define QSCALE  0.18033688011112042f

__device__ __forceinline__ u16 f2b(float f) {
  unsigned u = __builtin_bit_cast(unsigned, f);
  u += 0x7fffu + ((u >> 16) & 1u);           // round-to-nearest-even
  return (u16)(u >> 16);
}

__device__ __forceinline__ unsigned cvtpk_bf16(float lo, float hi) {
  unsigned r;
  asm("v_cvt_pk_bf16_f32 %0, %1, %2" : "=v"(r) : "v"(lo), "v"(hi));
  return r;
}

__device__ __forceinline__ f32x4 mfma16(bf16x4 a, bf16x4 b, f32x4 c) {
#if __has_builtin(__builtin_amdgcn_mfma_f32_16x16x16bf16_1k)
  return __builtin_amdgcn_mfma_f32_16x16x16bf16_1k(
      __builtin_bit_cast(s16x4, a), __builtin_bit_cast(s16x4, b), c, 0, 0, 0);
#else
  asm volatile("s_nop 1\n\tv_mfma_f32_16x16x16_bf16 %0, %1, %2, %0"
               : "+v"(c) : "v"(a), "v"(b));
  return c;
#endif
}

__device__ __forceinline__ void gload_lds16(const u16* g, u16* l) {
  __builtin_amdgcn_global_load_lds(
      (const __attribute__((address_space(1))) unsigned int*)g,
      (__attribute__((address_space(3))) unsigned int*)l, 16, 0, 0);
}

// ---------------- fp32 -> bf16 convert (4 elems/thread) ----------------
__global__ __launch_bounds__(256) void cvt_kernel(const float* __restrict__ in,
                                                  u16* __restrict__ out, int n4) {
  int i = blockIdx.x * 256 + threadIdx.x;
  if (i >= n4) return;
  float4 v = ((const float4*)in)[i];
  u16x4 o;
  o[0] = f2b(v.x); o[1] = f2b(v.y); o[2] = f2b(v.z); o[3] = f2b(v.w);
  ((u16x4*)out)[i] = o;
}

// ---------------- generic bf16 GEMM: C[M,N] = A[M,K] @ B[N,K]^T ----------------
// 128x128 tile, BK=64, 4 waves, 16x16x32 MFMA, global_load_lds(16B),
// XOR slot-swizzle applied to the GLOBAL source (LDS stays linear) + same XOR on reads.
// MODE 0: QKV. col<1024: Q*QSCALE -> qk (LD 2048); col<2048: K -> qk; else V -> vt transposed
// MODE 1: o = acc + resid[idx]; outf = o; outb = bf16(o)     (attn out + residual)
// MODE 2: o = relu(acc + bias[col]); outb = bf16(o)          (mlp in)
// MODE 3: outf = acc + resid[idx] + bias[col]                (mlp out -> d_out)
template<int MODE>
__global__ __launch_bounds__(256) void gemm_bt(
    const u16* __restrict__ A, const u16* __restrict__ Bw,
    int M, int N, int K,
    u16* __restrict__ outb, float* __restrict__ outf,
    const float* __restrict__ resid, const float* __restrict__ bias,
    u16* __restrict__ vtp)
{
  __shared__ u16 Asm_[128 * 64];
  __shared__ u16 Bsm_[128 * 64];
  const int t = threadIdx.x;
  const int lane = t & 63;
  const int l15 = lane & 15, l4 = lane >> 4;
  const int w = t >> 6;
  const int wr = w >> 1, wc = w & 1;
  const int m0 = blockIdx.y * 128;
  const int n0 = blockIdx.x * 128;

  f32x4 acc[4][4] = {};

  for (int k0 = 0; k0 < K; k0 += 64) {
    __syncthreads();
#pragma unroll
    for (int i = 0; i < 4; ++i) {
      int s = i * 256 + t;                 // 16B slot index 0..1023
      int row = s >> 3;
      int sl = s & 7;
      int gc = ((sl ^ (row & 7)) << 3);    // pre-swizzled global k-chunk
      const u16* ga = A + (size_t)(m0 + row) * K + (k0 + gc);
      const u16* gb = Bw + (size_t)(n0 + row) * K + (k0 + gc);
      u16* la = Asm_ + (i * 256 + (t & ~63)) * 8;   // wave-uniform base
      u16* lb = Bsm_ + (i * 256 + (t & ~63)) * 8;
      gload_lds16(ga, la);
      gload_lds16(gb, lb);
    }
    asm volatile("s_waitcnt vmcnt(0)" ::: "memory");
    __syncthreads();
#pragma unroll
    for (int kk = 0; kk < 2; ++kk) {
      bf16x8 af[4], bfr[4];
#pragma unroll
      for (int mi = 0; mi < 4; ++mi) {
        int row = wr * 64 + mi * 16 + l15;
        int sl2 = (kk * 4 + l4) ^ (row & 7);
        u16x8 ua = *(const u16x8*)(Asm_ + row * 64 + sl2 * 8);
        af[mi] = __builtin_bit_cast(bf16x8, ua);
      }
#pragma unroll
      for (int ni = 0; ni < 4; ++ni) {
        int row = wc * 64 + ni * 16 + l15;
        int sl2 = (kk * 4 + l4) ^ (row & 7);
        u16x8 ub = *(const u16x8*)(Bsm_ + row * 64 + sl2 * 8);
        bfr[ni] = __builtin_bit_cast(bf16x8, ub);
      }
#pragma unroll
      for (int mi = 0; mi < 4; ++mi)
#pragma unroll
        for (int ni = 0; ni < 4; ++ni)
          acc[mi][ni] = __builtin_amdgcn_mfma_f32_16x16x32_bf16(af[mi], bfr[ni], acc[mi][ni], 0, 0, 0);
    }
  }

#pragma unroll
  for (int mi = 0; mi < 4; ++mi) {
    int rowb = m0 + wr * 64 + mi * 16 + l4 * 4;
#pragma unroll
    for (int ni = 0; ni < 4; ++ni) {
      int col = n0 + wc * 64 + ni * 16 + l15;
#pragma unroll
      for (int r = 0; r < 4; ++r) {
        float v = acc[mi][ni][r];
        int row = rowb + r;
        if (MODE == 0) {
          if (col < 2048) {
            float o = (col < 1024) ? v * QSCALE : v;
            outb[((size_t)row << 11) + col] = f2b(o);
          } else {
            int c = col - 2048;                       // c = h*64 + d
            size_t vi = (((size_t)((row >> 11) * 1024 + c)) << 11) + (row & (SEQ - 1));
            vtp[vi] = f2b(v);
          }
        } else {
          size_t idx = (size_t)row * N + col;
          if (MODE == 1) {
            float o = v + resid[idx];
            outf[idx] = o;
            outb[idx] = f2b(o);
          } else if (MODE == 2) {
            float o = v + bias[col];
            o = o > 0.f ? o : 0.f;
            outb[idx] = f2b(o);
          } else {
            outf[idx] = v + resid[idx] + bias[col];
          }
        }
      }
    }
  }
}

// ---------------- causal flash attention, LDS-free, double-buffered ----------------
// One wave per (b, h, 16 query rows). Key tiles of 32.
// qk layout [BS][2048]: Q(prescaled)|K.  vT layout [(b*16+h)*64 + d][SEQ].
// Scores TRANSPOSED: sf = mfma(K, Q) -> lane holds S[p=sub*16+l4*4+r][q=l15]:
// softmax stats end up uniform across the 4 l4-groups per q.
// PV also TRANSPOSED: zacc = mfma(V^T-frag, P-frag) -> z^T[d = dn*16+l4*4+r][q=l15],
// so the online rescale needs NO shuffles at all.
struct KV {
  bf16x8 k00, k01, k10, k11;
  u16x4 v0a, v0b, v1a, v1b, v2a, v2b, v3a, v3b;
};

__global__ __launch_bounds__(256) void attn_kernel(const u16* __restrict__ qk,
                                                   const u16* __restrict__ vT,
                                                   u16* __restrict__ zb)
{
  const int t = threadIdx.x;
  const int w = t >> 6;
  const int lane = t & 63;
  const int l15 = lane & 15, l4 = lane >> 4;
  const int uu = blockIdx.x * 4 + w;
  const int qt = 127 - (uu >> 5);         // longest-first dispatch order
  const int bh = uu & 31;
  const int b = bh >> 4, h = bh & 15;
  const int q0 = qt * 16;

  // Q fragments (B-operand of the score mfma): Q[q0+l15][kc*32 + l4*8 .. +7]
  const u16* qptr = qk + (((size_t)(b * SEQ + q0 + l15)) << 11) + h * 64 + l4 * 8;
  const bf16x8 qf0 = __builtin_bit_cast(bf16x8, *(const u16x8*)(qptr));
  const bf16x8 qf1 = __builtin_bit_cast(bf16x8, *(const u16x8*)(qptr + 32));

  // K row base (A-operand): K[p + sub*16 + l15][l4*8 (+32)]
  const u16* kbase = qk + (((size_t)(b * SEQ + l15)) << 11) + 1024 + h * 64 + l4 * 8;
  // V^T row bases (A-operand of transposed PV): vT[d = dn*16 + l15][p + sub*16 + l4*4]
  const u16* vb0 = vT + ((((size_t)bh) * 64 +  0 + l15) << 11) + l4 * 4;
  const u16* vb1 = vT + ((((size_t)bh) * 64 + 16 + l15) << 11) + l4 * 4;
  const u16* vb2 = vT + ((((size_t)bh) * 64 + 32 + l15) << 11) + l4 * 4;
  const u16* vb3 = vT + ((((size_t)bh) * 64 + 48 + l15) << 11) + l4 * 4;

  auto load_kv = [&](int p0) {
    KV T;
    const u16* kr = kbase + ((size_t)p0 << 11);
    T.k00 = __builtin_bit_cast(bf16x8, *(const u16x8*)(kr));
    T.k01 = __builtin_bit_cast(bf16x8, *(const u16x8*)(kr + 32));
    T.k10 = __builtin_bit_cast(bf16x8, *(const u16x8*)(kr + ((size_t)16 << 11)));
    T.k11 = __builtin_bit_cast(bf16x8, *(const u16x8*)(kr + ((size_t)16 << 11) + 32));
    T.v0a = *(const u16x4*)(vb0 + p0); T.v0b = *(const u16x4*)(vb0 + p0 + 16);
    T.v1a = *(const u16x4*)(vb1 + p0); T.v1b = *(const u16x4*)(vb1 + p0 + 16);
    T.v2a = *(const u16x4*)(vb2 + p0); T.v2b = *(const u16x4*)(vb2 + p0 + 16);
    T.v3a = *(const u16x4*)(vb3 + p0); T.v3b = *(const u16x4*)(vb3 + p0 + 16);
    return T;
  };

  f32x4 zacc[4] = {};
  float m_run = -1e30f, l_run = 0.f;

  auto compute = [&](const KV& T, int p0, bool last) {
    f32x4 s0 = {}, s1 = {};
    s0 = __builtin_amdgcn_mfma_f32_16x16x32_bf16(T.k00, qf0, s0, 0, 0, 0);
    s0 = __builtin_amdgcn_mfma_f32_16x16x32_bf16(T.k01, qf1, s0, 0, 0, 0);
    s1 = __builtin_amdgcn_mfma_f32_16x16x32_bf16(T.k10, qf0, s1, 0, 0, 0);
    s1 = __builtin_amdgcn_mfma_f32_16x16x32_bf16(T.k11, qf1, s1, 0, 0, 0);

    if (last) {                           // only the diagonal tile needs the mask
      const int qq = q0 + l15;
      const int pb = p0 + l4 * 4;
#pragma unroll
      for (int r = 0; r < 4; ++r) {
        s0[r] = (pb + r <= qq) ? s0[r] : -1e30f;
        s1[r] = (pb + 16 + r <= qq) ? s1[r] : -1e30f;
      }
    }

    // online softmax over p; after xor16+xor32 the stats are uniform per q=l15
    float mt = fmaxf(fmaxf(fmaxf(s0[0], s0[1]), fmaxf(s0[2], s0[3])),
                     fmaxf(fmaxf(s1[0], s1[1]), fmaxf(s1[2], s1[3])));
    mt = fmaxf(mt, __shfl_xor(mt, 16));
    mt = fmaxf(mt, __shfl_xor(mt, 32));
    const float mn = fmaxf(m_run, mt);
    const float sc = __builtin_amdgcn_exp2f(m_run - mn);
    m_run = mn;
    float p0v[4], p1v[4];
    float rs = 0.f;
#pragma unroll
    for (int r = 0; r < 4; ++r) {
      p0v[r] = __builtin_amdgcn_exp2f(s0[r] - mn);
      p1v[r] = __builtin_amdgcn_exp2f(s1[r] - mn);
      rs += p0v[r] + p1v[r];
    }
    rs += __shfl_xor(rs, 16);
    rs += __shfl_xor(rs, 32);
    l_run = l_run * sc + rs;

    // shuffle-free rescale (sc uniform across the l4 groups of this q)
#pragma unroll
    for (int dn = 0; dn < 4; ++dn)
#pragma unroll
      for (int r = 0; r < 4; ++r) zacc[dn][r] *= sc;

    // pack P to bf16 frags (k=p quad = sub*16 + l4*4 .. +3, col=q=l15)
    u32x2 ua, ub2;
    ua[0]  = cvtpk_bf16(p0v[0], p0v[1]);
    ua[1]  = cvtpk_bf16(p0v[2], p0v[3]);
    ub2[0] = cvtpk_bf16(p1v[0], p1v[1]);
    ub2[1] = cvtpk_bf16(p1v[2], p1v[3]);
    const bf16x4 pa0 = __builtin_bit_cast(bf16x4, ua);
    const bf16x4 pa1 = __builtin_bit_cast(bf16x4, ub2);

    // transposed PV: zacc[dn] = z^T[d = dn*16 + l4*4+r][q = l15]
    zacc[0] = mfma16(__builtin_bit_cast(bf16x4, T.v0a), pa0, zacc[0]);
    zacc[0] = mfma16(__builtin_bit_cast(bf16x4, T.v0b), pa1, zacc[0]);
    zacc[1] = mfma16(__builtin_bit_cast(bf16x4, T.v1a), pa0, zacc[1]);
    zacc[1] = mfma16(__builtin_bit_cast(bf16x4, T.v1b), pa1, zacc[1]);
    zacc[2] = mfma16(__builtin_bit_cast(bf16x4, T.v2a), pa0, zacc[2]);
    zacc[2] = mfma16(__builtin_bit_cast(bf16x4, T.v2b), pa1, zacc[2]);
    zacc[3] = mfma16(__builtin_bit_cast(bf16x4, T.v3a), pa0, zacc[3]);
    zacc[3] = mfma16(__builtin_bit_cast(bf16x4, T.v3b), pa1, zacc[3]);
  };

  const int nfull = q0 >> 5;              // tiles 0..nfull; only nfull is masked
  KV cur = load_kv(0);
#pragma unroll 2
  for (int pt = 0; pt < nfull; ++pt) {
    KV nxt = load_kv((pt + 1) * 32);      // issue next-tile loads BEFORE compute
    compute(cur, pt * 32, false);
    cur = nxt;
  }
  compute(cur, nfull * 32, true);

  // epilogue: z[q = l15][h*64 + dn*16 + l4*4 + r], l_run uniform per q
  const float inv = 1.f / l_run;
  const size_t rowoff = ((size_t)(b * SEQ + q0 + l15)) * D_MODEL + h * 64 + l4 * 4;
#pragma unroll
  for (int dn = 0; dn < 4; ++dn) {
    u16x4 o;
#pragma unroll
    for (int r = 0; r < 4; ++r) o[r] = f2b(zacc[dn][r] * inv);
    *(u16x4*)(zb + rowoff + dn * 16) = o;
  }
}

// ---------------- launch ----------------
extern "C" void kernel_launch(void* const* d_in, const int* in_sizes, int n_in,
                              void* d_out, int out_size, void* d_ws, size_t ws_size,
                              hipStream_t stream) {
  const float* x     = (const float*)d_in[0];
  const float* W_K   = (const float*)d_in[1];
  const float* W_Q   = (const float*)d_in[2];
  const float* W_V   = (const float*)d_in[3];
  const float* W_O   = (const float*)d_in[4];
  const float* W_in  = (const float*)d_in[5];
  const float* b_in  = (const float*)d_in[6];
  const float* W_out = (const float*)d_in[7];
  const float* b_out = (const float*)d_in[8];
  float* out = (float*)d_out;

  char* p = (char*)d_ws;
  u16* xb    = (u16*)p;            p += (size_t)BS * D_MODEL * 2;
  u16* wqkv  = (u16*)p;            p += (size_t)QKV_N * D_MODEL * 2;
  u16* wo_b  = (u16*)p;            p += (size_t)D_MODEL * D_MODEL * 2;
  u16* win_b = (u16*)p;            p += (size_t)D_MLP * D_MODEL * 2;
  u16* wout_b= (u16*)p;            p += (size_t)D_MODEL * D_MLP * 2;
  u16* qk    = (u16*)p;            p += (size_t)BS * 2048 * 2;        // Q|K, LD 2048
  u16* vt    = (u16*)p;            p += (size_t)BATCH * 1024 * SEQ * 2; // V^T per (b,h,d)
  u16* zb    = (u16*)p;            p += (size_t)BS * D_MODEL * 2;
  float* x1f = (float*)p;          p += (size_t)BS * D_MODEL * 4;
  u16* x1b   = (u16*)p;            p += (size_t)BS * D_MODEL * 2;
  u16* hb    = (u16*)p;            p += (size_t)BS * D_MLP * 2;

  auto cvt = [&](const float* src, u16* dst, int n) {
    int n4 = n / 4;
    cvt_kernel<<<(n4 + 255) / 256, 256, 0, stream>>>(src, dst, n4);
  };
  cvt(x, xb, BS * D_MODEL);
  cvt(W_Q, wqkv + 0,                  N_HEADS * D_HEAD * D_MODEL);
  cvt(W_K, wqkv + 1024 * 1024,        N_HEADS * D_HEAD * D_MODEL);
  cvt(W_V, wqkv + 2 * 1024 * 1024,    N_HEADS * D_HEAD * D_MODEL);
  cvt(W_O, wo_b,  D_MODEL * D_MODEL);
  cvt(W_in, win_b, D_MLP * D_MODEL);
  cvt(W_out, wout_b, D_MODEL * D_MLP);

  // QKV projection: [4096,1024] @ [3072,1024]^T -> qk (Q prescaled | K) + vt (V^T)
  gemm_bt<0><<<dim3(QKV_N / 128, BS / 128), 256, 0, stream>>>(
      xb, wqkv, BS, QKV_N, D_MODEL, qk, nullptr, nullptr, nullptr, vt);

  // attention: 4096 wave-units / 4 per block
  attn_kernel<<<dim3(BS * N_HEADS / 16 / 4), 256, 0, stream>>>(qk, vt, zb);

  // attn out + residual: z @ W_O^T + x -> x1 (f32 + bf16)
  gemm_bt<1><<<dim3(D_MODEL / 128, BS / 128), 256, 0, stream>>>(
      zb, wo_b, BS, D_MODEL, D_MODEL, x1b, x1f, x, nullptr, nullptr);

  // MLP in: relu(x1 @ W_in^T + b_in) -> h
  gemm_bt<2><<<dim3(D_MLP / 128, BS / 128), 256, 0, stream>>>(
      x1b, win_b, BS, D_MLP, D_MODEL, hb, nullptr, nullptr, b_in, nullptr);

  // MLP out: x1 + h @ W_out^T + b_out -> out (f32)
  gemm_bt<3><<<dim3(D_MODEL / 128, BS / 128), 256, 0, stream>>>(
      hb, wout_b, BS, D_MODEL, D_MLP, nullptr, out, x1f, b_out, nullptr);
}

// Round 4
// 300.745 us; speedup vs baseline: 1.4232x; 1.4229x over previous
//
#include <hip/hip_runtime.h>

typedef unsigned short u16;
typedef __bf16 bf16x8 __attribute__((ext_vector_type(8)));
typedef __bf16 bf16x4 __attribute__((ext_vector_type(4)));
typedef float f32x4 __attribute__((ext_vector_type(4)));
typedef u16 u16x8 __attribute__((ext_vector_type(8), may_alias));
typedef u16 u16x4 __attribute__((ext_vector_type(4), may_alias));
typedef unsigned int u32x2 __attribute__((ext_vector_type(2)));
typedef short s16x4 __attribute__((ext_vector_type(4)));

#define D_MODEL 1024
#define D_MLP   4096
#define D_HEAD  64
#define N_HEADS 16
#define SEQ     2048
#define BATCH   2
#define BS      (BATCH * SEQ)   // 4096 rows
#define QKV_N   3072
// Q pre-scale: (1/sqrt(64)) * log2(e) so attention works in exp2 domain
#define QSCALE  0.18033688011112042f

__device__ __forceinline__ u16 f2b(float f) {
  unsigned u = __builtin_bit_cast(unsigned, f);
  u += 0x7fffu + ((u >> 16) & 1u);           // round-to-nearest-even
  return (u16)(u >> 16);
}

__device__ __forceinline__ unsigned cvtpk_bf16(float lo, float hi) {
  unsigned r;
  asm("v_cvt_pk_bf16_f32 %0, %1, %2" : "=v"(r) : "v"(lo), "v"(hi));
  return r;
}

__device__ __forceinline__ f32x4 mfma16(bf16x4 a, bf16x4 b, f32x4 c) {
#if __has_builtin(__builtin_amdgcn_mfma_f32_16x16x16bf16_1k)
  return __builtin_amdgcn_mfma_f32_16x16x16bf16_1k(
      __builtin_bit_cast(s16x4, a), __builtin_bit_cast(s16x4, b), c, 0, 0, 0);
#else
  asm volatile("s_nop 1\n\tv_mfma_f32_16x16x16_bf16 %0, %1, %2, %0"
               : "+v"(c) : "v"(a), "v"(b));
  return c;
#endif
}

__device__ __forceinline__ void gload_lds16(const u16* g, u16* l) {
  __builtin_amdgcn_global_load_lds(
      (const __attribute__((address_space(1))) unsigned int*)g,
      (__attribute__((address_space(3))) unsigned int*)l, 16, 0, 0);
}

// ---------------- fp32 -> bf16 convert (4 elems/thread) ----------------
__global__ __launch_bounds__(256) void cvt_kernel(const float* __restrict__ in,
                                                  u16* __restrict__ out, int n4) {
  int i = blockIdx.x * 256 + threadIdx.x;
  if (i >= n4) return;
  float4 v = ((const float4*)in)[i];
  u16x4 o;
  o[0] = f2b(v.x); o[1] = f2b(v.y); o[2] = f2b(v.z); o[3] = f2b(v.w);
  ((u16x4*)out)[i] = o;
}

// ---------------- generic bf16 GEMM: C[M,N] = A[M,K] @ B[N,K]^T ----------------
// 128x128 tile, BK=64, 4 waves, 16x16x32 MFMA, global_load_lds(16B),
// XOR slot-swizzle applied to the GLOBAL source (LDS stays linear) + same XOR on reads.
// MODE 0: QKV. col<1024: Q*QSCALE -> qk (LD 2048); col<2048: K -> qk; else V -> vt transposed
// MODE 1: o = acc + resid[idx]; outf = o; outb = bf16(o)     (attn out + residual)
// MODE 2: o = relu(acc + bias[col]); outb = bf16(o)          (mlp in)
// MODE 3: outf = acc + resid[idx] + bias[col]                (mlp out -> d_out)
template<int MODE>
__global__ __launch_bounds__(256) void gemm_bt(
    const u16* __restrict__ A, const u16* __restrict__ Bw,
    int M, int N, int K,
    u16* __restrict__ outb, float* __restrict__ outf,
    const float* __restrict__ resid, const float* __restrict__ bias,
    u16* __restrict__ vtp)
{
  __shared__ u16 Asm_[128 * 64];
  __shared__ u16 Bsm_[128 * 64];
  const int t = threadIdx.x;
  const int lane = t & 63;
  const int l15 = lane & 15, l4 = lane >> 4;
  const int w = t >> 6;
  const int wr = w >> 1, wc = w & 1;
  const int m0 = blockIdx.y * 128;
  const int n0 = blockIdx.x * 128;

  f32x4 acc[4][4] = {};

  for (int k0 = 0; k0 < K; k0 += 64) {
    __syncthreads();
#pragma unroll
    for (int i = 0; i < 4; ++i) {
      int s = i * 256 + t;                 // 16B slot index 0..1023
      int row = s >> 3;
      int sl = s & 7;
      int gc = ((sl ^ (row & 7)) << 3);    // pre-swizzled global k-chunk
      const u16* ga = A + (size_t)(m0 + row) * K + (k0 + gc);
      const u16* gb = Bw + (size_t)(n0 + row) * K + (k0 + gc);
      u16* la = Asm_ + (i * 256 + (t & ~63)) * 8;   // wave-uniform base
      u16* lb = Bsm_ + (i * 256 + (t & ~63)) * 8;
      gload_lds16(ga, la);
      gload_lds16(gb, lb);
    }
    asm volatile("s_waitcnt vmcnt(0)" ::: "memory");
    __syncthreads();
#pragma unroll
    for (int kk = 0; kk < 2; ++kk) {
      bf16x8 af[4], bfr[4];
#pragma unroll
      for (int mi = 0; mi < 4; ++mi) {
        int row = wr * 64 + mi * 16 + l15;
        int sl2 = (kk * 4 + l4) ^ (row & 7);
        u16x8 ua = *(const u16x8*)(Asm_ + row * 64 + sl2 * 8);
        af[mi] = __builtin_bit_cast(bf16x8, ua);
      }
#pragma unroll
      for (int ni = 0; ni < 4; ++ni) {
        int row = wc * 64 + ni * 16 + l15;
        int sl2 = (kk * 4 + l4) ^ (row & 7);
        u16x8 ub = *(const u16x8*)(Bsm_ + row * 64 + sl2 * 8);
        bfr[ni] = __builtin_bit_cast(bf16x8, ub);
      }
#pragma unroll
      for (int mi = 0; mi < 4; ++mi)
#pragma unroll
        for (int ni = 0; ni < 4; ++ni)
          acc[mi][ni] = __builtin_amdgcn_mfma_f32_16x16x32_bf16(af[mi], bfr[ni], acc[mi][ni], 0, 0, 0);
    }
  }

#pragma unroll
  for (int mi = 0; mi < 4; ++mi) {
    int rowb = m0 + wr * 64 + mi * 16 + l4 * 4;
#pragma unroll
    for (int ni = 0; ni < 4; ++ni) {
      int col = n0 + wc * 64 + ni * 16 + l15;
#pragma unroll
      for (int r = 0; r < 4; ++r) {
        float v = acc[mi][ni][r];
        int row = rowb + r;
        if (MODE == 0) {
          if (col < 2048) {
            float o = (col < 1024) ? v * QSCALE : v;
            outb[((size_t)row << 11) + col] = f2b(o);
          } else {
            int c = col - 2048;                       // c = h*64 + d
            size_t vi = (((size_t)((row >> 11) * 1024 + c)) << 11) + (row & (SEQ - 1));
            vtp[vi] = f2b(v);
          }
        } else {
          size_t idx = (size_t)row * N + col;
          if (MODE == 1) {
            float o = v + resid[idx];
            outf[idx] = o;
            outb[idx] = f2b(o);
          } else if (MODE == 2) {
            float o = v + bias[col];
            o = o > 0.f ? o : 0.f;
            outb[idx] = f2b(o);
          } else {
            outf[idx] = v + resid[idx] + bias[col];
          }
        }
      }
    }
  }
}

// ---------------- causal flash attention, block-shared LDS K/V ----------------
// Block = 4 waves x 32 q-rows = 128 q-rows of one (b,h) share each staged K/V tile.
// Key tiles of 32, double-buffered LDS: K [32][64] u16 XOR-swizzled (gload_lds,
// pre-swizzled global source), V^T [64][40] u16 padded (reg-staged).
// Scores TRANSPOSED (mfma(K,Q)) -> softmax stats uniform per q; PV TRANSPOSED
// (mfma(V,P)) -> shuffle-free rescale. Wave w computes tiles pt <= 4*qb + w.
__global__ __launch_bounds__(256) void attn_kernel(const u16* __restrict__ qk,
                                                   const u16* __restrict__ vT,
                                                   u16* __restrict__ zb)
{
  __shared__ u16 Kl[2][32 * 64];
  __shared__ u16 Vl[2][64 * 40];
  const int t = threadIdx.x;
  const int w = t >> 6;
  const int lane = t & 63;
  const int l15 = lane & 15, l4 = lane >> 4;
  const int blk = blockIdx.x;
  const int bh = blk & 31;
  const int qb = 15 - (blk >> 5);         // longest blocks first
  const int b = bh >> 4, h = bh & 15;
  const int q0w = qb * 128 + w * 32;
  const int myLast = 4 * qb + w;          // this wave's diagonal tile
  const int ptmax = 4 * qb + 3;

  // Q fragments: qf[sub][kc] for q rows q0w + sub*16 + l15
  bf16x8 qf[2][2];
#pragma unroll
  for (int s = 0; s < 2; ++s) {
    const u16* qp = qk + (((size_t)(b * SEQ + q0w + s * 16 + l15)) << 11) + h * 64 + l4 * 8;
    qf[s][0] = __builtin_bit_cast(bf16x8, *(const u16x8*)(qp));
    qf[s][1] = __builtin_bit_cast(bf16x8, *(const u16x8*)(qp + 32));
  }

  // staging addresses
  const int srow = t >> 3;                 // K tile row 0..31
  const int sgc = ((t & 7) ^ (srow & 7)) * 8;   // pre-swizzled k-chunk
  const u16* kgbase = qk + (((size_t)(b * SEQ + srow)) << 11) + 1024 + h * 64 + sgc;
  u16* kldst = &Kl[0][0] + (t & ~63) * 8;  // wave-uniform base (HW adds lane*16B)
  const int vd = t >> 2, vch = (t & 3) * 8;
  const u16* vgbase = vT + (((size_t)(bh * 64 + vd)) << 11) + vch;

  f32x4 zacc[2][4] = {};
  float m_run[2] = {-1e30f, -1e30f}, l_run[2] = {0.f, 0.f};

  auto compute = [&](int buf, int pt) {
    // K fragments from LDS (swizzled read)
    bf16x8 kf[2][2];
#pragma unroll
    for (int ks = 0; ks < 2; ++ks) {
      int row = ks * 16 + l15;
#pragma unroll
      for (int kc = 0; kc < 2; ++kc) {
        int slot = (kc * 4 + l4) ^ (row & 7);
        kf[ks][kc] = __builtin_bit_cast(bf16x8, *(const u16x8*)&Kl[buf][row * 64 + slot * 8]);
      }
    }
    // V fragments from LDS (padded rows)
    bf16x4 vf[2][4];
#pragma unroll
    for (int ks = 0; ks < 2; ++ks)
#pragma unroll
      for (int dn = 0; dn < 4; ++dn)
        vf[ks][dn] = __builtin_bit_cast(bf16x4,
            *(const u16x4*)&Vl[buf][(dn * 16 + l15) * 40 + ks * 16 + l4 * 4]);

    const bool diag = (pt == myLast);
#pragma unroll
    for (int s = 0; s < 2; ++s) {
      f32x4 s0 = {}, s1 = {};
      s0 = __builtin_amdgcn_mfma_f32_16x16x32_bf16(kf[0][0], qf[s][0], s0, 0, 0, 0);
      s0 = __builtin_amdgcn_mfma_f32_16x16x32_bf16(kf[0][1], qf[s][1], s0, 0, 0, 0);
      s1 = __builtin_amdgcn_mfma_f32_16x16x32_bf16(kf[1][0], qf[s][0], s1, 0, 0, 0);
      s1 = __builtin_amdgcn_mfma_f32_16x16x32_bf16(kf[1][1], qf[s][1], s1, 0, 0, 0);

      if (diag) {
        // tile p0 == q0w; sub 0: s0 triangular, s1 fully masked; sub 1: s1 triangular
#pragma unroll
        for (int r = 0; r < 4; ++r) {
          const bool keep = (l4 * 4 + r <= l15);
          if (s == 0) {
            s0[r] = keep ? s0[r] : -1e30f;
            s1[r] = -1e30f;
          } else {
            s1[r] = keep ? s1[r] : -1e30f;
          }
        }
      }

      float mt = fmaxf(fmaxf(fmaxf(s0[0], s0[1]), fmaxf(s0[2], s0[3])),
                       fmaxf(fmaxf(s1[0], s1[1]), fmaxf(s1[2], s1[3])));
      mt = fmaxf(mt, __shfl_xor(mt, 16));
      mt = fmaxf(mt, __shfl_xor(mt, 32));
      const float mn = fmaxf(m_run[s], mt);
      const float sc = __builtin_amdgcn_exp2f(m_run[s] - mn);
      m_run[s] = mn;
      float p0v[4], p1v[4];
      float rs = 0.f;
#pragma unroll
      for (int r = 0; r < 4; ++r) {
        p0v[r] = __builtin_amdgcn_exp2f(s0[r] - mn);
        p1v[r] = __builtin_amdgcn_exp2f(s1[r] - mn);
        rs += p0v[r] + p1v[r];
      }
      rs += __shfl_xor(rs, 16);
      rs += __shfl_xor(rs, 32);
      l_run[s] = l_run[s] * sc + rs;

#pragma unroll
      for (int dn = 0; dn < 4; ++dn)
#pragma unroll
        for (int r = 0; r < 4; ++r) zacc[s][dn][r] *= sc;

      u32x2 ua, ub2;
      ua[0]  = cvtpk_bf16(p0v[0], p0v[1]);
      ua[1]  = cvtpk_bf16(p0v[2], p0v[3]);
      ub2[0] = cvtpk_bf16(p1v[0], p1v[1]);
      ub2[1] = cvtpk_bf16(p1v[2], p1v[3]);
      const bf16x4 pa0 = __builtin_bit_cast(bf16x4, ua);
      const bf16x4 pa1 = __builtin_bit_cast(bf16x4, ub2);

#pragma unroll
      for (int dn = 0; dn < 4; ++dn) {
        zacc[s][dn] = mfma16(vf[0][dn], pa0, zacc[s][dn]);
        zacc[s][dn] = mfma16(vf[1][dn], pa1, zacc[s][dn]);
      }
    }
  };

  // prologue: stage tile 0
  gload_lds16(kgbase, kldst);
  {
    u16x8 v0 = *(const u16x8*)(vgbase);
    *(u16x8*)&Vl[0][vd * 40 + vch] = v0;
  }
  asm volatile("s_waitcnt vmcnt(0)" ::: "memory");
  __syncthreads();

  int cur = 0;
  for (int pt = 0; pt <= ptmax; ++pt) {
    const bool more = pt < ptmax;
    u16x8 vnext;
    if (more) {
      gload_lds16(kgbase + ((size_t)(pt + 1) << 16), kldst + (cur ^ 1) * (32 * 64));
      vnext = *(const u16x8*)(vgbase + (pt + 1) * 32);
    }
    if (pt <= myLast) compute(cur, pt);
    if (more) *(u16x8*)&Vl[cur ^ 1][vd * 40 + vch] = vnext;
    asm volatile("s_waitcnt vmcnt(0)" ::: "memory");
    __syncthreads();
    cur ^= 1;
  }

  // epilogue: z[q][h*64 + d], stats uniform per q
#pragma unroll
  for (int s = 0; s < 2; ++s) {
    const float inv = 1.f / l_run[s];
    const size_t rowoff = ((size_t)(b * SEQ + q0w + s * 16 + l15)) * D_MODEL + h * 64 + l4 * 4;
#pragma unroll
    for (int dn = 0; dn < 4; ++dn) {
      u16x4 o;
#pragma unroll
      for (int r = 0; r < 4; ++r) o[r] = f2b(zacc[s][dn][r] * inv);
      *(u16x4*)(zb + rowoff + dn * 16) = o;
    }
  }
}

// ---------------- launch ----------------
extern "C" void kernel_launch(void* const* d_in, const int* in_sizes, int n_in,
                              void* d_out, int out_size, void* d_ws, size_t ws_size,
                              hipStream_t stream) {
  const float* x     = (const float*)d_in[0];
  const float* W_K   = (const float*)d_in[1];
  const float* W_Q   = (const float*)d_in[2];
  const float* W_V   = (const float*)d_in[3];
  const float* W_O   = (const float*)d_in[4];
  const float* W_in  = (const float*)d_in[5];
  const float* b_in  = (const float*)d_in[6];
  const float* W_out = (const float*)d_in[7];
  const float* b_out = (const float*)d_in[8];
  float* out = (float*)d_out;

  char* p = (char*)d_ws;
  u16* xb    = (u16*)p;            p += (size_t)BS * D_MODEL * 2;
  u16* wqkv  = (u16*)p;            p += (size_t)QKV_N * D_MODEL * 2;
  u16* wo_b  = (u16*)p;            p += (size_t)D_MODEL * D_MODEL * 2;
  u16* win_b = (u16*)p;            p += (size_t)D_MLP * D_MODEL * 2;
  u16* wout_b= (u16*)p;            p += (size_t)D_MODEL * D_MLP * 2;
  u16* qk    = (u16*)p;            p += (size_t)BS * 2048 * 2;        // Q|K, LD 2048
  u16* vt    = (u16*)p;            p += (size_t)BATCH * 1024 * SEQ * 2; // V^T per (b,h,d)
  u16* zb    = (u16*)p;            p += (size_t)BS * D_MODEL * 2;
  float* x1f = (float*)p;          p += (size_t)BS * D_MODEL * 4;
  u16* x1b   = (u16*)p;            p += (size_t)BS * D_MODEL * 2;
  u16* hb    = (u16*)p;            p += (size_t)BS * D_MLP * 2;

  auto cvt = [&](const float* src, u16* dst, int n) {
    int n4 = n / 4;
    cvt_kernel<<<(n4 + 255) / 256, 256, 0, stream>>>(src, dst, n4);
  };
  cvt(x, xb, BS * D_MODEL);
  cvt(W_Q, wqkv + 0,                  N_HEADS * D_HEAD * D_MODEL);
  cvt(W_K, wqkv + 1024 * 1024,        N_HEADS * D_HEAD * D_MODEL);
  cvt(W_V, wqkv + 2 * 1024 * 1024,    N_HEADS * D_HEAD * D_MODEL);
  cvt(W_O, wo_b,  D_MODEL * D_MODEL);
  cvt(W_in, win_b, D_MLP * D_MODEL);
  cvt(W_out, wout_b, D_MODEL * D_MLP);

  // QKV projection: [4096,1024] @ [3072,1024]^T -> qk (Q prescaled | K) + vt (V^T)
  gemm_bt<0><<<dim3(QKV_N / 128, BS / 128), 256, 0, stream>>>(
      xb, wqkv, BS, QKV_N, D_MODEL, qk, nullptr, nullptr, nullptr, vt);

  // attention: 32 bh x 16 q-blocks (128 rows each)
  attn_kernel<<<dim3(512), 256, 0, stream>>>(qk, vt, zb);

  // attn out + residual: z @ W_O^T + x -> x1 (f32 + bf16)
  gemm_bt<1><<<dim3(D_MODEL / 128, BS / 128), 256, 0, stream>>>(
      zb, wo_b, BS, D_MODEL, D_MODEL, x1b, x1f, x, nullptr, nullptr);

  // MLP in: relu(x1 @ W_in^T + b_in) -> h
  gemm_bt<2><<<dim3(D_MLP / 128, BS / 128), 256, 0, stream>>>(
      x1b, win_b, BS, D_MLP, D_MODEL, hb, nullptr, nullptr, b_in, nullptr);

  // MLP out: x1 + h @ W_out^T + b_out -> out (f32)
  gemm_bt<3><<<dim3(D_MODEL / 128, BS / 128), 256, 0, stream>>>(
      hb, wout_b, BS, D_MODEL, D_MLP, nullptr, out, x1f, b_out, nullptr);
}

// Round 5
// 285.116 us; speedup vs baseline: 1.5012x; 1.0548x over previous
//
#include <hip/hip_runtime.h>

typedef unsigned short u16;
typedef __bf16 bf16x8 __attribute__((ext_vector_type(8)));
typedef __bf16 bf16x4 __attribute__((ext_vector_type(4)));
typedef float f32x4 __attribute__((ext_vector_type(4)));
typedef u16 u16x8 __attribute__((ext_vector_type(8), may_alias));
typedef u16 u16x4 __attribute__((ext_vector_type(4), may_alias));
typedef unsigned int u32x2 __attribute__((ext_vector_type(2)));
typedef short s16x4 __attribute__((ext_vector_type(4)));

#define D_MODEL 1024
#define D_MLP   4096
#define D_HEAD  64
#define N_HEADS 16
#define SEQ     2048
#define BATCH   2
#define BS      (BATCH * SEQ)   // 4096 rows
#define QKV_N   3072
// Q pre-scale: (1/sqrt(64)) * log2(e) so attention works in exp2 domain
#define QSCALE  0.18033688011112042f

__device__ __forceinline__ u16 f2b(float f) {
  unsigned u = __builtin_bit_cast(unsigned, f);
  u += 0x7fffu + ((u >> 16) & 1u);           // round-to-nearest-even
  return (u16)(u >> 16);
}

__device__ __forceinline__ unsigned cvtpk_bf16(float lo, float hi) {
  unsigned r;
  asm("v_cvt_pk_bf16_f32 %0, %1, %2" : "=v"(r) : "v"(lo), "v"(hi));
  return r;
}

__device__ __forceinline__ f32x4 mfma16(bf16x4 a, bf16x4 b, f32x4 c) {
#if __has_builtin(__builtin_amdgcn_mfma_f32_16x16x16bf16_1k)
  return __builtin_amdgcn_mfma_f32_16x16x16bf16_1k(
      __builtin_bit_cast(s16x4, a), __builtin_bit_cast(s16x4, b), c, 0, 0, 0);
#else
  asm volatile("s_nop 1\n\tv_mfma_f32_16x16x16_bf16 %0, %1, %2, %0"
               : "+v"(c) : "v"(a), "v"(b));
  return c;
#endif
}

__device__ __forceinline__ void gload_lds16(const u16* g, u16* l) {
  __builtin_amdgcn_global_load_lds(
      (const __attribute__((address_space(1))) unsigned int*)g,
      (__attribute__((address_space(3))) unsigned int*)l, 16, 0, 0);
}

// ---------------- fp32 -> bf16 convert (4 elems/thread) ----------------
__global__ __launch_bounds__(256) void cvt_kernel(const float* __restrict__ in,
                                                  u16* __restrict__ out, int n4) {
  int i = blockIdx.x * 256 + threadIdx.x;
  if (i >= n4) return;
  float4 v = ((const float4*)in)[i];
  u16x4 o;
  o[0] = f2b(v.x); o[1] = f2b(v.y); o[2] = f2b(v.z); o[3] = f2b(v.w);
  ((u16x4*)out)[i] = o;
}

// ---------------- generic bf16 GEMM: C[M,N] = A[M,K] @ B[N,K]^T ----------------
// 128x128 tile, BK=64, 4 waves, 16x16x32 MFMA, global_load_lds(16B),
// XOR slot-swizzle applied to the GLOBAL source (LDS stays linear) + same XOR on reads.
// 1D grid + XCD/supertile remap: xcd = bid&7 owns a 16-row x (gx/4)-col rectangle
// of 128x128 tiles, iterated column-major (B-panel L2-hot for 16 blocks).
// MODE 0: QKV. col<1024: Q*QSCALE -> qk (LD 2048); col<2048: K -> qk; else V -> vt transposed
// MODE 1: o = acc + resid[idx]; outf = o; outb = bf16(o)     (attn out + residual)
// MODE 2: o = relu(acc + bias[col]); outb = bf16(o)          (mlp in)
// MODE 3: split-K=2 (virtual gx=16, z=bx>>3): partial f32 -> outf[z*M*N + idx]
template<int MODE>
__global__ __launch_bounds__(256) void gemm_bt(
    const u16* __restrict__ A, const u16* __restrict__ Bw,
    int M, int N, int K,
    u16* __restrict__ outb, float* __restrict__ outf,
    const float* __restrict__ resid, const float* __restrict__ bias,
    u16* __restrict__ vtp, int gx)
{
  __shared__ u16 Asm_[128 * 64];
  __shared__ u16 Bsm_[128 * 64];
  const int t = threadIdx.x;
  const int lane = t & 63;
  const int l15 = lane & 15, l4 = lane >> 4;
  const int w = t >> 6;
  const int wr = w >> 1, wc = w & 1;

  // XCD/supertile remap (gy = 32 rows always; RY=2, CX=4, rh=16)
  const int xcd = blockIdx.x & 7;
  const int local = blockIdx.x >> 3;
  const int rw = gx >> 2;
  const int rx = xcd & 3, ry = xcd >> 2;
  const int c = local >> 4, r0 = local & 15;
  int bx = rx * rw + c;
  const int by = ry * 16 + r0;
  int z = 0;
  if (MODE == 3) { z = bx >> 3; bx &= 7; }
  const int m0 = by * 128;
  const int n0 = bx * 128;
  const int kb = (MODE == 3) ? z * (K >> 1) : 0;
  const int ke = (MODE == 3) ? kb + (K >> 1) : K;

  f32x4 acc[4][4] = {};

  for (int k0 = kb; k0 < ke; k0 += 64) {
    __syncthreads();
#pragma unroll
    for (int i = 0; i < 4; ++i) {
      int s = i * 256 + t;                 // 16B slot index 0..1023
      int row = s >> 3;
      int sl = s & 7;
      int gc = ((sl ^ (row & 7)) << 3);    // pre-swizzled global k-chunk
      const u16* ga = A + (size_t)(m0 + row) * K + (k0 + gc);
      const u16* gb = Bw + (size_t)(n0 + row) * K + (k0 + gc);
      u16* la = Asm_ + (i * 256 + (t & ~63)) * 8;   // wave-uniform base
      u16* lb = Bsm_ + (i * 256 + (t & ~63)) * 8;
      gload_lds16(ga, la);
      gload_lds16(gb, lb);
    }
    asm volatile("s_waitcnt vmcnt(0)" ::: "memory");
    __syncthreads();
#pragma unroll
    for (int kk = 0; kk < 2; ++kk) {
      bf16x8 af[4], bfr[4];
#pragma unroll
      for (int mi = 0; mi < 4; ++mi) {
        int row = wr * 64 + mi * 16 + l15;
        int sl2 = (kk * 4 + l4) ^ (row & 7);
        u16x8 ua = *(const u16x8*)(Asm_ + row * 64 + sl2 * 8);
        af[mi] = __builtin_bit_cast(bf16x8, ua);
      }
#pragma unroll
      for (int ni = 0; ni < 4; ++ni) {
        int row = wc * 64 + ni * 16 + l15;
        int sl2 = (kk * 4 + l4) ^ (row & 7);
        u16x8 ub = *(const u16x8*)(Bsm_ + row * 64 + sl2 * 8);
        bfr[ni] = __builtin_bit_cast(bf16x8, ub);
      }
#pragma unroll
      for (int mi = 0; mi < 4; ++mi)
#pragma unroll
        for (int ni = 0; ni < 4; ++ni)
          acc[mi][ni] = __builtin_amdgcn_mfma_f32_16x16x32_bf16(af[mi], bfr[ni], acc[mi][ni], 0, 0, 0);
    }
  }

#pragma unroll
  for (int mi = 0; mi < 4; ++mi) {
    int rowb = m0 + wr * 64 + mi * 16 + l4 * 4;
#pragma unroll
    for (int ni = 0; ni < 4; ++ni) {
      int col = n0 + wc * 64 + ni * 16 + l15;
#pragma unroll
      for (int r = 0; r < 4; ++r) {
        float v = acc[mi][ni][r];
        int row = rowb + r;
        if (MODE == 0) {
          if (col < 2048) {
            float o = (col < 1024) ? v * QSCALE : v;
            outb[((size_t)row << 11) + col] = f2b(o);
          } else {
            int c2 = col - 2048;                      // c2 = h*64 + d
            size_t vi = (((size_t)((row >> 11) * 1024 + c2)) << 11) + (row & (SEQ - 1));
            vtp[vi] = f2b(v);
          }
        } else if (MODE == 3) {
          outf[(size_t)z * M * N + (size_t)row * N + col] = v;
        } else {
          size_t idx = (size_t)row * N + col;
          if (MODE == 1) {
            float o = v + resid[idx];
            outf[idx] = o;
            outb[idx] = f2b(o);
          } else {
            float o = v + bias[col];
            o = o > 0.f ? o : 0.f;
            outb[idx] = f2b(o);
          }
        }
      }
    }
  }
}

// ---------------- split-K reduce: out = p0 + p1 + resid + bias ----------------
__global__ __launch_bounds__(256) void reduce2_kernel(const float* __restrict__ part,
                                                      const float* __restrict__ resid,
                                                      const float* __restrict__ bias,
                                                      float* __restrict__ out) {
  const int i = blockIdx.x * 256 + threadIdx.x;    // float4 index over BS*1024/4
  float4 a = ((const float4*)part)[i];
  float4 b = ((const float4*)(part + (size_t)BS * D_MODEL))[i];
  float4 r = ((const float4*)resid)[i];
  float4 bi = ((const float4*)bias)[i & 255];      // D_MODEL/4 = 256
  float4 o;
  o.x = a.x + b.x + r.x + bi.x;
  o.y = a.y + b.y + r.y + bi.y;
  o.z = a.z + b.z + r.z + bi.z;
  o.w = a.w + b.w + r.w + bi.w;
  ((float4*)out)[i] = o;
}

// ---------------- causal flash attention, block-shared LDS K/V ----------------
// Block = 4 waves x 32 q-rows = 128 q-rows of one (b,h) share each staged K/V tile.
// Key tiles of 32, double-buffered LDS: K [32][64] u16 XOR-swizzled (gload_lds,
// pre-swizzled global source), V^T [64][40] u16 padded (reg-staged).
// Scores TRANSPOSED (mfma(K,Q)) -> softmax stats uniform per q; PV TRANSPOSED
// (mfma(V,P)) -> shuffle-free rescale. Wave w computes tiles pt <= 4*qb + w.
__global__ __launch_bounds__(256) void attn_kernel(const u16* __restrict__ qk,
                                                   const u16* __restrict__ vT,
                                                   u16* __restrict__ zb)
{
  __shared__ u16 Kl[2][32 * 64];
  __shared__ u16 Vl[2][64 * 40];
  const int t = threadIdx.x;
  const int w = t >> 6;
  const int lane = t & 63;
  const int l15 = lane & 15, l4 = lane >> 4;
  const int blk = blockIdx.x;
  const int bh = blk & 31;
  const int qb = 15 - (blk >> 5);         // longest blocks first
  const int b = bh >> 4, h = bh & 15;
  const int q0w = qb * 128 + w * 32;
  const int myLast = 4 * qb + w;          // this wave's diagonal tile
  const int ptmax = 4 * qb + 3;

  // Q fragments: qf[sub][kc] for q rows q0w + sub*16 + l15
  bf16x8 qf[2][2];
#pragma unroll
  for (int s = 0; s < 2; ++s) {
    const u16* qp = qk + (((size_t)(b * SEQ + q0w + s * 16 + l15)) << 11) + h * 64 + l4 * 8;
    qf[s][0] = __builtin_bit_cast(bf16x8, *(const u16x8*)(qp));
    qf[s][1] = __builtin_bit_cast(bf16x8, *(const u16x8*)(qp + 32));
  }

  // staging addresses
  const int srow = t >> 3;                 // K tile row 0..31
  const int sgc = ((t & 7) ^ (srow & 7)) * 8;   // pre-swizzled k-chunk
  const u16* kgbase = qk + (((size_t)(b * SEQ + srow)) << 11) + 1024 + h * 64 + sgc;
  u16* kldst = &Kl[0][0] + (t & ~63) * 8;  // wave-uniform base (HW adds lane*16B)
  const int vd = t >> 2, vch = (t & 3) * 8;
  const u16* vgbase = vT + (((size_t)(bh * 64 + vd)) << 11) + vch;

  f32x4 zacc[2][4] = {};
  float m_run[2] = {-1e30f, -1e30f}, l_run[2] = {0.f, 0.f};

  auto compute = [&](int buf, int pt) {
    // K fragments from LDS (swizzled read)
    bf16x8 kf[2][2];
#pragma unroll
    for (int ks = 0; ks < 2; ++ks) {
      int row = ks * 16 + l15;
#pragma unroll
      for (int kc = 0; kc < 2; ++kc) {
        int slot = (kc * 4 + l4) ^ (row & 7);
        kf[ks][kc] = __builtin_bit_cast(bf16x8, *(const u16x8*)&Kl[buf][row * 64 + slot * 8]);
      }
    }
    // V fragments from LDS (padded rows)
    bf16x4 vf[2][4];
#pragma unroll
    for (int ks = 0; ks < 2; ++ks)
#pragma unroll
      for (int dn = 0; dn < 4; ++dn)
        vf[ks][dn] = __builtin_bit_cast(bf16x4,
            *(const u16x4*)&Vl[buf][(dn * 16 + l15) * 40 + ks * 16 + l4 * 4]);

    const bool diag = (pt == myLast);
#pragma unroll
    for (int s = 0; s < 2; ++s) {
      f32x4 s0 = {}, s1 = {};
      s0 = __builtin_amdgcn_mfma_f32_16x16x32_bf16(kf[0][0], qf[s][0], s0, 0, 0, 0);
      s0 = __builtin_amdgcn_mfma_f32_16x16x32_bf16(kf[0][1], qf[s][1], s0, 0, 0, 0);
      s1 = __builtin_amdgcn_mfma_f32_16x16x32_bf16(kf[1][0], qf[s][0], s1, 0, 0, 0);
      s1 = __builtin_amdgcn_mfma_f32_16x16x32_bf16(kf[1][1], qf[s][1], s1, 0, 0, 0);

      if (diag) {
        // tile p0 == q0w; sub 0: s0 triangular, s1 fully masked; sub 1: s1 triangular
#pragma unroll
        for (int r = 0; r < 4; ++r) {
          const bool keep = (l4 * 4 + r <= l15);
          if (s == 0) {
            s0[r] = keep ? s0[r] : -1e30f;
            s1[r] = -1e30f;
          } else {
            s1[r] = keep ? s1[r] : -1e30f;
          }
        }
      }

      float mt = fmaxf(fmaxf(fmaxf(s0[0], s0[1]), fmaxf(s0[2], s0[3])),
                       fmaxf(fmaxf(s1[0], s1[1]), fmaxf(s1[2], s1[3])));
      mt = fmaxf(mt, __shfl_xor(mt, 16));
      mt = fmaxf(mt, __shfl_xor(mt, 32));
      const float mn = fmaxf(m_run[s], mt);
      const float sc = __builtin_amdgcn_exp2f(m_run[s] - mn);
      m_run[s] = mn;
      float p0v[4], p1v[4];
      float rs = 0.f;
#pragma unroll
      for (int r = 0; r < 4; ++r) {
        p0v[r] = __builtin_amdgcn_exp2f(s0[r] - mn);
        p1v[r] = __builtin_amdgcn_exp2f(s1[r] - mn);
        rs += p0v[r] + p1v[r];
      }
      rs += __shfl_xor(rs, 16);
      rs += __shfl_xor(rs, 32);
      l_run[s] = l_run[s] * sc + rs;

#pragma unroll
      for (int dn = 0; dn < 4; ++dn)
#pragma unroll
        for (int r = 0; r < 4; ++r) zacc[s][dn][r] *= sc;

      u32x2 ua, ub2;
      ua[0]  = cvtpk_bf16(p0v[0], p0v[1]);
      ua[1]  = cvtpk_bf16(p0v[2], p0v[3]);
      ub2[0] = cvtpk_bf16(p1v[0], p1v[1]);
      ub2[1] = cvtpk_bf16(p1v[2], p1v[3]);
      const bf16x4 pa0 = __builtin_bit_cast(bf16x4, ua);
      const bf16x4 pa1 = __builtin_bit_cast(bf16x4, ub2);

#pragma unroll
      for (int dn = 0; dn < 4; ++dn) {
        zacc[s][dn] = mfma16(vf[0][dn], pa0, zacc[s][dn]);
        zacc[s][dn] = mfma16(vf[1][dn], pa1, zacc[s][dn]);
      }
    }
  };

  // prologue: stage tile 0
  gload_lds16(kgbase, kldst);
  {
    u16x8 v0 = *(const u16x8*)(vgbase);
    *(u16x8*)&Vl[0][vd * 40 + vch] = v0;
  }
  asm volatile("s_waitcnt vmcnt(0)" ::: "memory");
  __syncthreads();

  int cur = 0;
  for (int pt = 0; pt <= ptmax; ++pt) {
    const bool more = pt < ptmax;
    u16x8 vnext;
    if (more) {
      gload_lds16(kgbase + ((size_t)(pt + 1) << 16), kldst + (cur ^ 1) * (32 * 64));
      vnext = *(const u16x8*)(vgbase + (pt + 1) * 32);
    }
    if (pt <= myLast) compute(cur, pt);
    if (more) *(u16x8*)&Vl[cur ^ 1][vd * 40 + vch] = vnext;
    asm volatile("s_waitcnt vmcnt(0)" ::: "memory");
    __syncthreads();
    cur ^= 1;
  }

  // epilogue: z[q][h*64 + d], stats uniform per q
#pragma unroll
  for (int s = 0; s < 2; ++s) {
    const float inv = 1.f / l_run[s];
    const size_t rowoff = ((size_t)(b * SEQ + q0w + s * 16 + l15)) * D_MODEL + h * 64 + l4 * 4;
#pragma unroll
    for (int dn = 0; dn < 4; ++dn) {
      u16x4 o;
#pragma unroll
      for (int r = 0; r < 4; ++r) o[r] = f2b(zacc[s][dn][r] * inv);
      *(u16x4*)(zb + rowoff + dn * 16) = o;
    }
  }
}

// ---------------- launch ----------------
extern "C" void kernel_launch(void* const* d_in, const int* in_sizes, int n_in,
                              void* d_out, int out_size, void* d_ws, size_t ws_size,
                              hipStream_t stream) {
  const float* x     = (const float*)d_in[0];
  const float* W_K   = (const float*)d_in[1];
  const float* W_Q   = (const float*)d_in[2];
  const float* W_V   = (const float*)d_in[3];
  const float* W_O   = (const float*)d_in[4];
  const float* W_in  = (const float*)d_in[5];
  const float* b_in  = (const float*)d_in[6];
  const float* W_out = (const float*)d_in[7];
  const float* b_out = (const float*)d_in[8];
  float* out = (float*)d_out;

  char* p = (char*)d_ws;
  u16* xb    = (u16*)p;            p += (size_t)BS * D_MODEL * 2;
  u16* wqkv  = (u16*)p;            p += (size_t)QKV_N * D_MODEL * 2;
  u16* wo_b  = (u16*)p;            p += (size_t)D_MODEL * D_MODEL * 2;
  u16* win_b = (u16*)p;            p += (size_t)D_MLP * D_MODEL * 2;
  u16* wout_b= (u16*)p;            p += (size_t)D_MODEL * D_MLP * 2;
  float* x1f = (float*)p;          p += (size_t)BS * D_MODEL * 4;
  u16* hb    = (u16*)p;            p += (size_t)BS * D_MLP * 2;
  // tail region: dead after their consumers; reused as split-K partials
  u16* qk    = (u16*)p;            p += (size_t)BS * 2048 * 2;        // Q|K, LD 2048
  u16* vt    = (u16*)p;            p += (size_t)BATCH * 1024 * SEQ * 2; // V^T per (b,h,d)
  u16* zb    = (u16*)p;            p += (size_t)BS * D_MODEL * 2;
  u16* x1b   = (u16*)p;            p += (size_t)BS * D_MODEL * 2;
  float* part = (float*)qk;        // 2 x BS x 1024 f32 = 33.6 MB over qk/vt/zb/x1b (40 MB)

  auto cvt = [&](const float* src, u16* dst, int n) {
    int n4 = n / 4;
    cvt_kernel<<<(n4 + 255) / 256, 256, 0, stream>>>(src, dst, n4);
  };
  cvt(x, xb, BS * D_MODEL);
  cvt(W_Q, wqkv + 0,                  N_HEADS * D_HEAD * D_MODEL);
  cvt(W_K, wqkv + 1024 * 1024,        N_HEADS * D_HEAD * D_MODEL);
  cvt(W_V, wqkv + 2 * 1024 * 1024,    N_HEADS * D_HEAD * D_MODEL);
  cvt(W_O, wo_b,  D_MODEL * D_MODEL);
  cvt(W_in, win_b, D_MLP * D_MODEL);
  cvt(W_out, wout_b, D_MODEL * D_MLP);

  // QKV projection: [4096,1024] @ [3072,1024]^T -> qk (Q prescaled | K) + vt (V^T)
  gemm_bt<0><<<dim3(24 * 32), 256, 0, stream>>>(
      xb, wqkv, BS, QKV_N, D_MODEL, qk, nullptr, nullptr, nullptr, vt, 24);

  // attention: 32 bh x 16 q-blocks (128 rows each)
  attn_kernel<<<dim3(512), 256, 0, stream>>>(qk, vt, zb);

  // attn out + residual: z @ W_O^T + x -> x1 (f32 + bf16)
  gemm_bt<1><<<dim3(8 * 32), 256, 0, stream>>>(
      zb, wo_b, BS, D_MODEL, D_MODEL, x1b, x1f, x, nullptr, nullptr, 8);

  // MLP in: relu(x1 @ W_in^T + b_in) -> h
  gemm_bt<2><<<dim3(32 * 32), 256, 0, stream>>>(
      x1b, win_b, BS, D_MLP, D_MODEL, hb, nullptr, nullptr, b_in, nullptr, 32);

  // MLP out, split-K=2: h @ W_out^T -> part[z]
  gemm_bt<3><<<dim3(16 * 32), 256, 0, stream>>>(
      hb, wout_b, BS, D_MODEL, D_MLP, nullptr, part, nullptr, nullptr, nullptr, 16);

  // out = part0 + part1 + x1 + b_out
  reduce2_kernel<<<dim3(BS * D_MODEL / 4 / 256), 256, 0, stream>>>(part, x1f, b_out, out);
}